// Round 2
// baseline (4634.250 us; speedup 1.0000x reference)
//
#include <hip/hip_runtime.h>
#include <stdint.h>

#define T_SEQ 128
#define B_SZ  32
#define H_DIM 1024
#define E_DIM 512
#define V_DIM 32000
#define SOS_TOK 1

typedef float v4f __attribute__((ext_vector_type(4)));
typedef short short8 __attribute__((ext_vector_type(8)));

// RNE float->bf16
__device__ inline uint16_t f2bf(float x) {
    uint32_t u = __float_as_uint(x);
    uint32_t r = (u + 0x7fffu + ((u >> 16) & 1u)) >> 16;
    return (uint16_t)r;
}
__device__ inline uint32_t pack2(float a, float b) {
    return (uint32_t)f2bf(a) | ((uint32_t)f2bf(b) << 16);
}

// async global->LDS, 16B per lane. lds base must be wave-uniform.
__device__ inline void gload16(const void* g, void* l) {
    __builtin_amdgcn_global_load_lds(
        (const __attribute__((address_space(1))) uint32_t*)g,
        (__attribute__((address_space(3))) uint32_t*)l, 16, 0, 0);
}

// ---------------------------------------------------------------------------
// ktrans: Wt[k][n] = W_hh[n][k]   (H x H)
// ---------------------------------------------------------------------------
__global__ __launch_bounds__(256) void ktrans(const float* __restrict__ W,
                                              float* __restrict__ Wt) {
    __shared__ float tile[32][33];
    int bx = blockIdx.x, by = blockIdx.y;
    int c = threadIdx.x & 31, r0 = threadIdx.x >> 5;
#pragma unroll
    for (int l = 0; l < 4; ++l) {
        int r = r0 + l * 8;
        tile[r][c] = W[(by * 32 + r) * H_DIM + bx * 32 + c];
    }
    __syncthreads();
#pragma unroll
    for (int l = 0; l < 4; ++l) {
        int r = r0 + l * 8;
        Wt[(bx * 32 + r) * H_DIM + by * 32 + c] = tile[c][r];
    }
}

// ---------------------------------------------------------------------------
// kxw: xW[m][n] = emb[tok(m)] . Wih[n] + bih[n] + bhh[n]
// fp32 128x128 tile, BK=16, 256 thr, 8x8 per thread, transpose-staged LDS.
// grid (32, 8)
// ---------------------------------------------------------------------------
__global__ __launch_bounds__(256) void kxw(const int* __restrict__ target,
                                           const float* __restrict__ emb,
                                           const float* __restrict__ Wih,
                                           const float* __restrict__ bih,
                                           const float* __restrict__ bhh,
                                           float* __restrict__ xW) {
    __shared__ __align__(16) float As[16][132];
    __shared__ __align__(16) float Bs[16][132];
    __shared__ int toks[128];
    int m0 = blockIdx.x * 128, n0 = blockIdx.y * 128;
    int tid = threadIdx.x;
    if (tid < 128) {
        int row = m0 + tid;
        int t = row & (T_SEQ - 1);
        toks[tid] = (t == 0) ? SOS_TOK : target[row];
    }
    __syncthreads();

    float acc[8][8] = {};
    int tm = (tid & 15) * 8, tn = (tid >> 4) * 8;

    float bias[8];
#pragma unroll
    for (int j = 0; j < 8; ++j) bias[j] = bih[n0 + tn + j] + bhh[n0 + tn + j];

    for (int k0 = 0; k0 < E_DIM; k0 += 16) {
        // stage A,B (transposed): 512 float4 each, 2 per thread
#pragma unroll
        for (int l = 0; l < 2; ++l) {
            int c = tid + l * 256;
            int r = c >> 2, kc = (c & 3) * 4;
            float4 av = *(const float4*)&emb[(size_t)toks[r] * E_DIM + k0 + kc];
            float4 bv = *(const float4*)&Wih[(size_t)(n0 + r) * E_DIM + k0 + kc];
            As[kc + 0][r] = av.x; As[kc + 1][r] = av.y;
            As[kc + 2][r] = av.z; As[kc + 3][r] = av.w;
            Bs[kc + 0][r] = bv.x; Bs[kc + 1][r] = bv.y;
            Bs[kc + 2][r] = bv.z; Bs[kc + 3][r] = bv.w;
        }
        __syncthreads();
#pragma unroll
        for (int k = 0; k < 16; ++k) {
            float4 a0 = *(const float4*)&As[k][tm];
            float4 a1 = *(const float4*)&As[k][tm + 4];
            float4 b0 = *(const float4*)&Bs[k][tn];
            float4 b1 = *(const float4*)&Bs[k][tn + 4];
            float a[8] = {a0.x, a0.y, a0.z, a0.w, a1.x, a1.y, a1.z, a1.w};
            float b[8] = {b0.x, b0.y, b0.z, b0.w, b1.x, b1.y, b1.z, b1.w};
#pragma unroll
            for (int i = 0; i < 8; ++i)
#pragma unroll
                for (int j = 0; j < 8; ++j) acc[i][j] += a[i] * b[j];
        }
        __syncthreads();
    }
#pragma unroll
    for (int i = 0; i < 8; ++i) {
        int m = m0 + tm + i;
        float4 o0, o1;
        o0.x = acc[i][0] + bias[0]; o0.y = acc[i][1] + bias[1];
        o0.z = acc[i][2] + bias[2]; o0.w = acc[i][3] + bias[3];
        o1.x = acc[i][4] + bias[4]; o1.y = acc[i][5] + bias[5];
        o1.z = acc[i][6] + bias[6]; o1.w = acc[i][7] + bias[7];
        *(float4*)&xW[(size_t)m * H_DIM + n0 + tn] = o0;
        *(float4*)&xW[(size_t)m * H_DIM + n0 + tn + 4] = o1;
    }
}

// ---------------------------------------------------------------------------
// krnn: one block per batch row b; all 128 steps in one launch.
// h in LDS (fp32). thread (kq = tid>>8, j = tid&255): partial over k-range
// [kq*256, kq*256+256) for 4 n-cols n = 4j..4j+3. LDS 4-way reduce.
// ---------------------------------------------------------------------------
__global__ __launch_bounds__(1024) void krnn(const float* __restrict__ h0,
                                             const float* __restrict__ Wt,
                                             const float* __restrict__ xW,
                                             uint16_t* __restrict__ Hb) {
    __shared__ __align__(16) float hl[H_DIM];
    __shared__ __align__(16) float red[1024][4];
    int b = blockIdx.x, tid = threadIdx.x;
    hl[tid] = h0[b * H_DIM + tid];
    __syncthreads();

    int kq = tid >> 8, j = tid & 255;
    int n4 = j * 4;
    const float* wbase = Wt + (size_t)(kq * 256) * H_DIM + n4;
    const float* hp = hl + kq * 256;

    for (int t = 0; t < T_SEQ; ++t) {
        float a0 = 0.f, a1 = 0.f, a2 = 0.f, a3 = 0.f;
#pragma unroll 4
        for (int k = 0; k < 256; k += 4) {
            float4 h4 = *(const float4*)&hp[k];
            float4 w0 = *(const float4*)&wbase[(size_t)(k + 0) * H_DIM];
            float4 w1 = *(const float4*)&wbase[(size_t)(k + 1) * H_DIM];
            float4 w2 = *(const float4*)&wbase[(size_t)(k + 2) * H_DIM];
            float4 w3 = *(const float4*)&wbase[(size_t)(k + 3) * H_DIM];
            a0 += h4.x * w0.x + h4.y * w1.x + h4.z * w2.x + h4.w * w3.x;
            a1 += h4.x * w0.y + h4.y * w1.y + h4.z * w2.y + h4.w * w3.y;
            a2 += h4.x * w0.z + h4.y * w1.z + h4.z * w2.z + h4.w * w3.z;
            a3 += h4.x * w0.w + h4.y * w1.w + h4.z * w2.w + h4.w * w3.w;
        }
        *(float4*)red[tid] = make_float4(a0, a1, a2, a3);
        __syncthreads();   // also guarantees all hl reads of this step done
        if (tid < 256) {
            float4 r0 = *(const float4*)red[tid];
            float4 r1 = *(const float4*)red[tid + 256];
            float4 r2 = *(const float4*)red[tid + 512];
            float4 r3 = *(const float4*)red[tid + 768];
            float4 xv = *(const float4*)&xW[(size_t)(b * T_SEQ + t) * H_DIM + tid * 4];
            float4 z;
            z.x = tanhf(r0.x + r1.x + r2.x + r3.x + xv.x);
            z.y = tanhf(r0.y + r1.y + r2.y + r3.y + xv.y);
            z.z = tanhf(r0.z + r1.z + r2.z + r3.z + xv.z);
            z.w = tanhf(r0.w + r1.w + r2.w + r3.w + xv.w);
            *(float4*)&hl[tid * 4] = z;
            uint2 p;
            p.x = pack2(z.x, z.y);
            p.y = pack2(z.z, z.w);
            *(uint2*)&Hb[(size_t)(b * T_SEQ + t) * H_DIM + tid * 4] = p;
        }
        __syncthreads();
    }
}

// ---------------------------------------------------------------------------
// kconv: W_out fp32 -> bf16
// ---------------------------------------------------------------------------
__global__ __launch_bounds__(256) void kconv(const float* __restrict__ W,
                                             uint16_t* __restrict__ Wb) {
    int i = (blockIdx.x * 256 + threadIdx.x) * 8;
    float4 a = *(const float4*)&W[i];
    float4 c = *(const float4*)&W[i + 4];
    uint4 p;
    p.x = pack2(a.x, a.y); p.y = pack2(a.z, a.w);
    p.z = pack2(c.x, c.y); p.w = pack2(c.z, c.w);
    *(uint4*)&Wb[i] = p;
}

// ---------------------------------------------------------------------------
// kgemm: out[m][v] = sum_k Hb[m][k] * Wout[v][k] + b_out[v]
// bf16 MFMA 16x16x32, 128x128 tile, BK=32, 4 waves.
// bid = nt*32 + mt  (nt-major: B panel HBM-streamed ~once).
// BBF=true: A and B staged via global_load_lds width-16.
// ---------------------------------------------------------------------------
template <bool BBF>
__global__ __launch_bounds__(256) void kgemm(const uint16_t* __restrict__ Ab,
                                             const void* __restrict__ Bp,
                                             const float* __restrict__ bout,
                                             float* __restrict__ out) {
    __shared__ __align__(16) uint16_t As[128 * 32];
    __shared__ __align__(16) uint16_t Bs[128 * 32];

    int bid = blockIdx.x;
    int nt = bid >> 5, mt = bid & 31;
    int m0 = mt * 128, n0 = nt * 128;
    int tid = threadIdx.x;
    int lane = tid & 63;

    const uint16_t* Bb = (const uint16_t*)Bp;
    const float*    Bf = (const float*)Bp;

    v4f acc[4][4] = {};
    int wv = tid >> 6, wm = wv >> 1, wn = wv & 1;
    int ar = lane & 15, ko = (lane >> 4) * 8;

    for (int k0 = 0; k0 < H_DIM; k0 += 32) {
        if constexpr (BBF) {
            int wb = tid & ~63;   // wave-uniform lane-block base (in 16B units)
#pragma unroll
            for (int l = 0; l < 2; ++l) {
                int c = tid + l * 256;
                int r = c >> 2, ko8 = (c & 3) * 8;
                gload16(&Ab[(size_t)(m0 + r) * H_DIM + k0 + ko8],
                        (char*)As + (size_t)(wb + l * 256) * 16);
                gload16(&Bb[(size_t)(n0 + r) * H_DIM + k0 + ko8],
                        (char*)Bs + (size_t)(wb + l * 256) * 16);
            }
        } else {
#pragma unroll
            for (int l = 0; l < 2; ++l) {
                int c = tid + l * 256;
                int r = c >> 2, ko8 = (c & 3) * 8;
                uint4 v = *(const uint4*)&Ab[(size_t)(m0 + r) * H_DIM + k0 + ko8];
                *(uint4*)&As[r * 32 + ko8] = v;
                const float* src = &Bf[(size_t)(n0 + r) * H_DIM + k0 + ko8];
                float4 x = *(const float4*)src;
                float4 y = *(const float4*)(src + 4);
                uint4 p;
                p.x = pack2(x.x, x.y); p.y = pack2(x.z, x.w);
                p.z = pack2(y.x, y.y); p.w = pack2(y.z, y.w);
                *(uint4*)&Bs[r * 32 + ko8] = p;
            }
        }
        __syncthreads();

        short8 a[4], bfr[4];
#pragma unroll
        for (int i = 0; i < 4; ++i)
            a[i] = *(const short8*)&As[(wm * 64 + i * 16 + ar) * 32 + ko];
#pragma unroll
        for (int jj = 0; jj < 4; ++jj)
            bfr[jj] = *(const short8*)&Bs[(wn * 64 + jj * 16 + ar) * 32 + ko];
#pragma unroll
        for (int i = 0; i < 4; ++i)
#pragma unroll
            for (int jj = 0; jj < 4; ++jj)
                acc[i][jj] = __builtin_amdgcn_mfma_f32_16x16x32_bf16(
                    a[i], bfr[jj], acc[i][jj], 0, 0, 0);
        __syncthreads();
    }

    int fr = lane & 15, fq = lane >> 4;
#pragma unroll
    for (int jj = 0; jj < 4; ++jj) {
        int col = n0 + wn * 64 + jj * 16 + fr;
        float bo = bout[col];
#pragma unroll
        for (int i = 0; i < 4; ++i) {
            int row = m0 + wm * 64 + i * 16 + fq * 4;
#pragma unroll
            for (int q = 0; q < 4; ++q)
                out[(size_t)(row + q) * V_DIM + col] = acc[i][jj][q] + bo;
        }
    }
}

// ---------------------------------------------------------------------------
extern "C" void kernel_launch(void* const* d_in, const int* in_sizes, int n_in,
                              void* d_out, int out_size, void* d_ws, size_t ws_size,
                              hipStream_t stream) {
    const int*   target = (const int*)d_in[0];
    const float* h0     = (const float*)d_in[1];
    const float* emb    = (const float*)d_in[2];
    const float* Wih    = (const float*)d_in[3];
    const float* bih    = (const float*)d_in[4];
    const float* Whh    = (const float*)d_in[5];
    const float* bhh    = (const float*)d_in[6];
    const float* Wout   = (const float*)d_in[7];
    const float* bout   = (const float*)d_in[8];
    float* out = (float*)d_out;

    char* ws = (char*)d_ws;
    float*    xW = (float*)(ws);                    // 16,777,216 B
    float*    Wt = (float*)(ws + 16777216);         //  4,194,304 B
    uint16_t* Hb = (uint16_t*)(ws + 20971520);      //  8,388,608 B
    uint16_t* Wb = (uint16_t*)(ws + 29360128);      // 65,536,000 B (optional)
    const bool use_wb = ws_size >= 94896128ull;

    ktrans<<<dim3(32, 32), 256, 0, stream>>>(Whh, Wt);
    kxw<<<dim3(32, 8), 256, 0, stream>>>(target, emb, Wih, bih, bhh, xW);
    krnn<<<B_SZ, 1024, 0, stream>>>(h0, Wt, xW, Hb);

    if (use_wb) {
        kconv<<<16000, 256, 0, stream>>>(Wout, Wb);
        kgemm<true><<<8000, 256, 0, stream>>>(Hb, (const void*)Wb, bout, out);
    } else {
        kgemm<false><<<8000, 256, 0, stream>>>(Hb, (const void*)Wout, bout, out);
    }
}

// Round 3
// 1722.652 us; speedup vs baseline: 2.6902x; 2.6902x over previous
//
#include <hip/hip_runtime.h>
#include <stdint.h>

#define T_SEQ 128
#define B_SZ  32
#define H_DIM 1024
#define E_DIM 512
#define V_DIM 32000
#define SOS_TOK 1
#define NBLK_RNN 32

typedef float v4f __attribute__((ext_vector_type(4)));
typedef short short8 __attribute__((ext_vector_type(8)));

// RNE float->bf16
__device__ inline uint16_t f2bf(float x) {
    uint32_t u = __float_as_uint(x);
    uint32_t r = (u + 0x7fffu + ((u >> 16) & 1u)) >> 16;
    return (uint16_t)r;
}
__device__ inline uint32_t pack2(float a, float b) {
    return (uint32_t)f2bf(a) | ((uint32_t)f2bf(b) << 16);
}

// async global->LDS, 16B per lane. lds base must be wave-uniform.
__device__ inline void gload16(const void* g, void* l) {
    __builtin_amdgcn_global_load_lds(
        (const __attribute__((address_space(1))) uint32_t*)g,
        (__attribute__((address_space(3))) uint32_t*)l, 16, 0, 0);
}

// ---------------------------------------------------------------------------
// kconv: fp32 -> bf16, 2048 elements per block (grid = count/2048)
// ---------------------------------------------------------------------------
__global__ __launch_bounds__(256) void kconv(const float* __restrict__ W,
                                             uint16_t* __restrict__ Wb) {
    size_t i = ((size_t)blockIdx.x * 256 + threadIdx.x) * 8;
    float4 a = *(const float4*)&W[i];
    float4 c = *(const float4*)&W[i + 4];
    uint4 p;
    p.x = pack2(a.x, a.y); p.y = pack2(a.z, a.w);
    p.z = pack2(c.x, c.y); p.w = pack2(c.z, c.w);
    *(uint4*)&Wb[i] = p;
}

// ---------------------------------------------------------------------------
// kxw: xW[m][n] = emb[tok(m)] . Wih[n] + bih[n] + bhh[n]
// fp32 128x128 tile, BK=16, 256 thr, 8x8 per thread. grid (32, 8)
// ---------------------------------------------------------------------------
__global__ __launch_bounds__(256) void kxw(const int* __restrict__ target,
                                           const float* __restrict__ emb,
                                           const float* __restrict__ Wih,
                                           const float* __restrict__ bih,
                                           const float* __restrict__ bhh,
                                           float* __restrict__ xW) {
    __shared__ __align__(16) float As[16][132];
    __shared__ __align__(16) float Bs[16][132];
    __shared__ int toks[128];
    int m0 = blockIdx.x * 128, n0 = blockIdx.y * 128;
    int tid = threadIdx.x;
    if (tid < 128) {
        int row = m0 + tid;
        int t = row & (T_SEQ - 1);
        toks[tid] = (t == 0) ? SOS_TOK : target[row];
    }
    __syncthreads();

    float acc[8][8] = {};
    int tm = (tid & 15) * 8, tn = (tid >> 4) * 8;

    float bias[8];
#pragma unroll
    for (int j = 0; j < 8; ++j) bias[j] = bih[n0 + tn + j] + bhh[n0 + tn + j];

    for (int k0 = 0; k0 < E_DIM; k0 += 16) {
#pragma unroll
        for (int l = 0; l < 2; ++l) {
            int c = tid + l * 256;
            int r = c >> 2, kc = (c & 3) * 4;
            float4 av = *(const float4*)&emb[(size_t)toks[r] * E_DIM + k0 + kc];
            float4 bv = *(const float4*)&Wih[(size_t)(n0 + r) * E_DIM + k0 + kc];
            As[kc + 0][r] = av.x; As[kc + 1][r] = av.y;
            As[kc + 2][r] = av.z; As[kc + 3][r] = av.w;
            Bs[kc + 0][r] = bv.x; Bs[kc + 1][r] = bv.y;
            Bs[kc + 2][r] = bv.z; Bs[kc + 3][r] = bv.w;
        }
        __syncthreads();
#pragma unroll
        for (int k = 0; k < 16; ++k) {
            float4 a0 = *(const float4*)&As[k][tm];
            float4 a1 = *(const float4*)&As[k][tm + 4];
            float4 b0 = *(const float4*)&Bs[k][tn];
            float4 b1 = *(const float4*)&Bs[k][tn + 4];
            float a[8] = {a0.x, a0.y, a0.z, a0.w, a1.x, a1.y, a1.z, a1.w};
            float b[8] = {b0.x, b0.y, b0.z, b0.w, b1.x, b1.y, b1.z, b1.w};
#pragma unroll
            for (int i = 0; i < 8; ++i)
#pragma unroll
                for (int j = 0; j < 8; ++j) acc[i][j] += a[i] * b[j];
        }
        __syncthreads();
    }
#pragma unroll
    for (int i = 0; i < 8; ++i) {
        int m = m0 + tm + i;
        float4 o0, o1;
        o0.x = acc[i][0] + bias[0]; o0.y = acc[i][1] + bias[1];
        o0.z = acc[i][2] + bias[2]; o0.w = acc[i][3] + bias[3];
        o1.x = acc[i][4] + bias[4]; o1.y = acc[i][5] + bias[5];
        o1.z = acc[i][6] + bias[6]; o1.w = acc[i][7] + bias[7];
        *(float4*)&xW[(size_t)m * H_DIM + n0 + tn] = o0;
        *(float4*)&xW[(size_t)m * H_DIM + n0 + tn + 4] = o1;
    }
}

// ---------------------------------------------------------------------------
// krnn: persistent recurrence. 32 blocks x 256 thr (4 waves), 1 launch.
// Block = (bg = blk&1: 16 batches, ngg = blk>>1: 64 n-cols). Wave w owns
// n-tile ngg*64 + w*16 (16 cols) x 16 batches x full K=1024.
// W_hh bf16 B-frags register-resident (32 x short8). Per step: 32 A-frags of
// h from global (16B/lane contiguous), 32 MFMA (4 interleaved accs), fp32
// +xW, tanh, republish h as bf16. Device barrier (monotonic counters) /step.
// ---------------------------------------------------------------------------
__global__ __launch_bounds__(256, 1) void krnn(const uint16_t* __restrict__ hbInit,
                                               const uint16_t* __restrict__ Wb,
                                               const float* __restrict__ xW,
                                               uint16_t* __restrict__ Hb,
                                               uint32_t* __restrict__ ctr) {
    int blk = blockIdx.x;
    int bg = blk & 1;
    int ngg = blk >> 1;
    int tid = threadIdx.x;
    int w = tid >> 6, lane = tid & 63;
    int ncol0 = ngg * 64 + w * 16;
    int lr = lane & 15, lk = (lane >> 4) * 8;

    // B-frags: lane holds Wb[ncol0+lr][kt*32 + lk + 0..7]  ([n][k] row-major,
    // same layout as the validated round-1 Bs fragment reads)
    short8 wf[32];
    const uint16_t* wrow = Wb + (size_t)(ncol0 + lr) * H_DIM + lk;
#pragma unroll
    for (int kt = 0; kt < 32; ++kt)
        wf[kt] = *(const short8*)(wrow + (size_t)kt * 32);

    int brow = bg * 16 + lr;              // A row (batch) this lane loads
    int eb = bg * 16 + (lane >> 4) * 4;   // epilogue batch base
    int en = ncol0 + lr;                  // epilogue out col

    for (int t = 0; t < T_SEQ; ++t) {
        const uint16_t* abase;
        size_t astride;
        if (t == 0) { abase = hbInit; astride = H_DIM; }
        else { abase = Hb + (size_t)(t - 1) * H_DIM; astride = (size_t)T_SEQ * H_DIM; }
        const uint16_t* arow = abase + (size_t)brow * astride + lk;

        v4f ac0 = {0.f,0.f,0.f,0.f}, ac1 = {0.f,0.f,0.f,0.f};
        v4f ac2 = {0.f,0.f,0.f,0.f}, ac3 = {0.f,0.f,0.f,0.f};
        short8 af[16];
#pragma unroll
        for (int kt = 0; kt < 16; ++kt)
            af[kt] = *(const short8*)(arow + (size_t)kt * 32);
#pragma unroll
        for (int kt = 0; kt < 16; ++kt) {
            v4f* a = (kt & 3) == 0 ? &ac0 : (kt & 3) == 1 ? &ac1 : (kt & 3) == 2 ? &ac2 : &ac3;
            *a = __builtin_amdgcn_mfma_f32_16x16x32_bf16(af[kt], wf[kt], *a, 0, 0, 0);
        }
#pragma unroll
        for (int kt = 0; kt < 16; ++kt)
            af[kt] = *(const short8*)(arow + 512 + (size_t)kt * 32);
#pragma unroll
        for (int kt = 0; kt < 16; ++kt) {
            v4f* a = (kt & 3) == 0 ? &ac0 : (kt & 3) == 1 ? &ac1 : (kt & 3) == 2 ? &ac2 : &ac3;
            *a = __builtin_amdgcn_mfma_f32_16x16x32_bf16(af[kt], wf[16 + kt], *a, 0, 0, 0);
        }
        v4f acc = (ac0 + ac1) + (ac2 + ac3);

        // epilogue: acc[q] -> batch eb+q, col en
#pragma unroll
        for (int q = 0; q < 4; ++q) {
            size_t oidx = ((size_t)(eb + q) * T_SEQ + t) * H_DIM + en;
            float hv = tanhf(acc[q] + xW[oidx]);
            Hb[oidx] = f2bf(hv);
        }

        if (t < T_SEQ - 1) {
            __threadfence();          // release: flush h stores to coherence pt
            __syncthreads();
            if (tid == 0) {
                __hip_atomic_fetch_add(&ctr[t], 1u, __ATOMIC_RELEASE,
                                       __HIP_MEMORY_SCOPE_AGENT);
                while (__hip_atomic_load(&ctr[t], __ATOMIC_RELAXED,
                                         __HIP_MEMORY_SCOPE_AGENT) < NBLK_RNN)
                    __builtin_amdgcn_s_sleep(1);
                __threadfence();      // acquire: invalidate L1/L2
            }
            __syncthreads();
        }
    }
}

// ---------------------------------------------------------------------------
// kgemm: out[m][gc0+n] = sum_k Hb[m][k] * WbChunk[n][k] + b_out[gc0+n]
// bf16 MFMA 16x16x32, 128x128 tile, BK=32, 4 waves, global_load_lds staging.
// Per chunk: 50 nt x 32 mt, bid = nt*32 + mt (A panel L3-reused).
// ---------------------------------------------------------------------------
__global__ __launch_bounds__(256) void kgemm(const uint16_t* __restrict__ Ab,
                                             const uint16_t* __restrict__ Bb,
                                             const float* __restrict__ bout,
                                             float* __restrict__ out,
                                             int gc0) {
    __shared__ __align__(16) uint16_t As[128 * 32];
    __shared__ __align__(16) uint16_t Bs[128 * 32];

    int bid = blockIdx.x;
    int nt = bid >> 5, mt = bid & 31;
    int m0 = mt * 128, n0 = nt * 128;
    int tid = threadIdx.x;
    int lane = tid & 63;

    v4f acc[4][4] = {};
    int wv = tid >> 6, wm = wv >> 1, wn = wv & 1;
    int ar = lane & 15, ko = (lane >> 4) * 8;

    for (int k0 = 0; k0 < H_DIM; k0 += 32) {
        int wb = tid & ~63;   // wave-uniform base (16B units)
#pragma unroll
        for (int l = 0; l < 2; ++l) {
            int c = tid + l * 256;
            int r = c >> 2, ko8 = (c & 3) * 8;
            gload16(&Ab[(size_t)(m0 + r) * H_DIM + k0 + ko8],
                    (char*)As + (size_t)(wb + l * 256) * 16);
            gload16(&Bb[(size_t)(n0 + r) * H_DIM + k0 + ko8],
                    (char*)Bs + (size_t)(wb + l * 256) * 16);
        }
        __syncthreads();

        short8 a[4], bfr[4];
#pragma unroll
        for (int i = 0; i < 4; ++i)
            a[i] = *(const short8*)&As[(wm * 64 + i * 16 + ar) * 32 + ko];
#pragma unroll
        for (int jj = 0; jj < 4; ++jj)
            bfr[jj] = *(const short8*)&Bs[(wn * 64 + jj * 16 + ar) * 32 + ko];
#pragma unroll
        for (int i = 0; i < 4; ++i)
#pragma unroll
            for (int jj = 0; jj < 4; ++jj)
                acc[i][jj] = __builtin_amdgcn_mfma_f32_16x16x32_bf16(
                    a[i], bfr[jj], acc[i][jj], 0, 0, 0);
        __syncthreads();
    }

    int fr = lane & 15, fq = lane >> 4;
#pragma unroll
    for (int jj = 0; jj < 4; ++jj) {
        int col = gc0 + n0 + wn * 64 + jj * 16 + fr;
        float bo = bout[col];
#pragma unroll
        for (int i = 0; i < 4; ++i) {
            int row = m0 + wm * 64 + i * 16 + fq * 4;
#pragma unroll
            for (int q = 0; q < 4; ++q)
                out[(size_t)(row + q) * V_DIM + col] = acc[i][jj][q] + bo;
        }
    }
}

// ---------------------------------------------------------------------------
extern "C" void kernel_launch(void* const* d_in, const int* in_sizes, int n_in,
                              void* d_out, int out_size, void* d_ws, size_t ws_size,
                              hipStream_t stream) {
    const int*   target = (const int*)d_in[0];
    const float* h0     = (const float*)d_in[1];
    const float* emb    = (const float*)d_in[2];
    const float* Wih    = (const float*)d_in[3];
    const float* bih    = (const float*)d_in[4];
    const float* Whh    = (const float*)d_in[5];
    const float* bhh    = (const float*)d_in[6];
    const float* Wout   = (const float*)d_in[7];
    const float* bout   = (const float*)d_in[8];
    float* out = (float*)d_out;

    char* ws = (char*)d_ws;
    // ws layout (bytes) — total 27,329,024 (fits proven >=29.3MB workspace):
    float*    xW     = (float*)(ws);                    // 16,777,216
    uint16_t* WbHH   = (uint16_t*)(ws + 16777216);      //  2,097,152
    uint16_t* hbInit = (uint16_t*)(ws + 18874368);      //     65,536
    uint32_t* ctr    = (uint32_t*)(ws + 18939904);      //        512
    uint16_t* Hb     = (uint16_t*)(ws + 18940416);      //  8,388,608
    uint16_t* WbOut  = (uint16_t*)(ws);                 // 13,107,200 (reuses dead xW)

    kconv<<<512, 256, 0, stream>>>(Whh, WbHH);       // 1,048,576 elts
    kconv<<<16, 256, 0, stream>>>(h0, hbInit);       //    32,768 elts
    kxw<<<dim3(32, 8), 256, 0, stream>>>(target, emb, Wih, bih, bhh, xW);
    hipMemsetAsync(ctr, 0, 512, stream);
    krnn<<<NBLK_RNN, 256, 0, stream>>>(hbInit, WbHH, xW, Hb, ctr);

    // decode GEMM in 5 column chunks of 6400 (WbOut lives in dead xW region)
    for (int c = 0; c < 5; ++c) {
        kconv<<<3200, 256, 0, stream>>>(Wout + (size_t)c * 6553600, WbOut);
        kgemm<<<1600, 256, 0, stream>>>(Hb, WbOut, bout, out, c * 6400);
    }
}

// Round 4
// 1296.782 us; speedup vs baseline: 3.5737x; 1.3284x over previous
//
#include <hip/hip_runtime.h>
#include <stdint.h>

#define T_SEQ 128
#define B_SZ  32
#define H_DIM 1024
#define E_DIM 512
#define V_DIM 32000
#define SOS_TOK 1

typedef float v4f __attribute__((ext_vector_type(4)));
typedef short short8 __attribute__((ext_vector_type(8)));

// RNE float->bf16
__device__ inline uint16_t f2bf(float x) {
    uint32_t u = __float_as_uint(x);
    uint32_t r = (u + 0x7fffu + ((u >> 16) & 1u)) >> 16;
    return (uint16_t)r;
}
__device__ inline uint32_t pack2(float a, float b) {
    return (uint32_t)f2bf(a) | ((uint32_t)f2bf(b) << 16);
}

// async global->LDS, 16B per lane. lds base must be wave-uniform.
__device__ inline void gload16(const void* g, void* l) {
    __builtin_amdgcn_global_load_lds(
        (const __attribute__((address_space(1))) uint32_t*)g,
        (__attribute__((address_space(3))) uint32_t*)l, 16, 0, 0);
}

// ---------------------------------------------------------------------------
// kconv: fp32 -> bf16, 2048 elements per block
// ---------------------------------------------------------------------------
__global__ __launch_bounds__(256) void kconv(const float* __restrict__ W,
                                             uint16_t* __restrict__ Wb) {
    size_t i = ((size_t)blockIdx.x * 256 + threadIdx.x) * 8;
    float4 a = *(const float4*)&W[i];
    float4 c = *(const float4*)&W[i + 4];
    uint4 p;
    p.x = pack2(a.x, a.y); p.y = pack2(a.z, a.w);
    p.z = pack2(c.x, c.y); p.w = pack2(c.z, c.w);
    *(uint4*)&Wb[i] = p;
}

// ---------------------------------------------------------------------------
// kxw: xW[m][n] = emb[tok(m)] . Wih[n] + bih[n] + bhh[n]
// fp32 128x128 tile, BK=16, 256 thr, 8x8 per thread. grid (32, 8)
// ---------------------------------------------------------------------------
__global__ __launch_bounds__(256) void kxw(const int* __restrict__ target,
                                           const float* __restrict__ emb,
                                           const float* __restrict__ Wih,
                                           const float* __restrict__ bih,
                                           const float* __restrict__ bhh,
                                           float* __restrict__ xW) {
    __shared__ __align__(16) float As[16][132];
    __shared__ __align__(16) float Bs[16][132];
    __shared__ int toks[128];
    int m0 = blockIdx.x * 128, n0 = blockIdx.y * 128;
    int tid = threadIdx.x;
    if (tid < 128) {
        int row = m0 + tid;
        int t = row & (T_SEQ - 1);
        toks[tid] = (t == 0) ? SOS_TOK : target[row];
    }
    __syncthreads();

    float acc[8][8] = {};
    int tm = (tid & 15) * 8, tn = (tid >> 4) * 8;

    float bias[8];
#pragma unroll
    for (int j = 0; j < 8; ++j) bias[j] = bih[n0 + tn + j] + bhh[n0 + tn + j];

    for (int k0 = 0; k0 < E_DIM; k0 += 16) {
#pragma unroll
        for (int l = 0; l < 2; ++l) {
            int c = tid + l * 256;
            int r = c >> 2, kc = (c & 3) * 4;
            float4 av = *(const float4*)&emb[(size_t)toks[r] * E_DIM + k0 + kc];
            float4 bv = *(const float4*)&Wih[(size_t)(n0 + r) * E_DIM + k0 + kc];
            As[kc + 0][r] = av.x; As[kc + 1][r] = av.y;
            As[kc + 2][r] = av.z; As[kc + 3][r] = av.w;
            Bs[kc + 0][r] = bv.x; Bs[kc + 1][r] = bv.y;
            Bs[kc + 2][r] = bv.z; Bs[kc + 3][r] = bv.w;
        }
        __syncthreads();
#pragma unroll
        for (int k = 0; k < 16; ++k) {
            float4 a0 = *(const float4*)&As[k][tm];
            float4 a1 = *(const float4*)&As[k][tm + 4];
            float4 b0 = *(const float4*)&Bs[k][tn];
            float4 b1 = *(const float4*)&Bs[k][tn + 4];
            float a[8] = {a0.x, a0.y, a0.z, a0.w, a1.x, a1.y, a1.z, a1.w};
            float b[8] = {b0.x, b0.y, b0.z, b0.w, b1.x, b1.y, b1.z, b1.w};
#pragma unroll
            for (int i = 0; i < 8; ++i)
#pragma unroll
                for (int j = 0; j < 8; ++j) acc[i][j] += a[i] * b[j];
        }
        __syncthreads();
    }
#pragma unroll
    for (int i = 0; i < 8; ++i) {
        int m = m0 + tm + i;
        float4 o0, o1;
        o0.x = acc[i][0] + bias[0]; o0.y = acc[i][1] + bias[1];
        o0.z = acc[i][2] + bias[2]; o0.w = acc[i][3] + bias[3];
        o1.x = acc[i][4] + bias[4]; o1.y = acc[i][5] + bias[5];
        o1.z = acc[i][6] + bias[6]; o1.w = acc[i][7] + bias[7];
        *(float4*)&xW[(size_t)m * H_DIM + n0 + tn] = o0;
        *(float4*)&xW[(size_t)m * H_DIM + n0 + tn + 4] = o1;
    }
}

// ---------------------------------------------------------------------------
// krnn: persistent recurrence. 32 blocks x 256 thr (4 waves), 1 launch.
// Block (bg = blk&1: 16 batches, ngg = blk>>1: 64 n-cols). Wave w owns
// n-tile ngg*64 + w*16. W_hh bf16 B-frags register-resident (32 x short8,
// unified VGPR/AGPR file absorbs them). Per step: 32 A-frags of h_{t-1} from
// global, 32 MFMA, +xW, tanh, publish h_t WRITE-THROUGH (4B agent-scope
// atomic stores, col-pair packed via shfl_xor). Barrier per step and per
// batch-group: distributed per-block monotonic flags (128B apart), arrival =
// one RELEASE store (tid0), wait = lanes 0..15 poll one flag each, then one
// ACQUIRE load (buffer_inv covers the CU's L1 + XCD L2 for the whole block).
// ---------------------------------------------------------------------------
__global__ __launch_bounds__(256, 1) void krnn(const uint16_t* __restrict__ hbInit,
                                               const uint16_t* __restrict__ Wb,
                                               const float* __restrict__ xW,
                                               uint16_t* __restrict__ Hb,
                                               uint32_t* __restrict__ flags) {
    int blk = blockIdx.x;
    int bg = blk & 1;
    int ngg = blk >> 1;
    int tid = threadIdx.x;
    int w = tid >> 6, lane = tid & 63;
    int ncol0 = ngg * 64 + w * 16;
    int lr = lane & 15, lk = (lane >> 4) * 8;

    // B-frags: lane holds Wb[ncol0+lr][kt*32 + lk + 0..7]
    short8 wf[32];
    const uint16_t* wrow = Wb + (size_t)(ncol0 + lr) * H_DIM + lk;
#pragma unroll
    for (int kt = 0; kt < 32; ++kt)
        wf[kt] = *(const short8*)(wrow + (size_t)kt * 32);

    int brow = bg * 16 + lr;              // A row (batch) this lane loads
    int eb = bg * 16 + (lane >> 4) * 4;   // epilogue batch base
    int en = ncol0 + lr;                  // epilogue out col
    uint32_t* Hb32 = (uint32_t*)Hb;
    uint32_t* myflag = flags + (size_t)(bg * 16 + ngg) * 32;  // 128B spacing
    const uint32_t* grpflags = flags + (size_t)(bg * 16) * 32;

    for (int t = 0; t < T_SEQ; ++t) {
        const uint16_t* abase;
        size_t astride;
        if (t == 0) { abase = hbInit; astride = H_DIM; }
        else { abase = Hb + (size_t)(t - 1) * H_DIM; astride = (size_t)T_SEQ * H_DIM; }
        const uint16_t* arow = abase + (size_t)brow * astride + lk;

        // xW prefetch (independent of h)
        float xv[4];
#pragma unroll
        for (int q = 0; q < 4; ++q)
            xv[q] = xW[((size_t)(eb + q) * T_SEQ + t) * H_DIM + en];

        v4f ac0 = {0.f,0.f,0.f,0.f}, ac1 = {0.f,0.f,0.f,0.f};
        v4f ac2 = {0.f,0.f,0.f,0.f}, ac3 = {0.f,0.f,0.f,0.f};
        short8 af[16];
#pragma unroll
        for (int kt = 0; kt < 16; ++kt)
            af[kt] = *(const short8*)(arow + (size_t)kt * 32);
#pragma unroll
        for (int kt = 0; kt < 16; ++kt) {
            v4f* a = (kt & 3) == 0 ? &ac0 : (kt & 3) == 1 ? &ac1 : (kt & 3) == 2 ? &ac2 : &ac3;
            *a = __builtin_amdgcn_mfma_f32_16x16x32_bf16(af[kt], wf[kt], *a, 0, 0, 0);
        }
#pragma unroll
        for (int kt = 0; kt < 16; ++kt)
            af[kt] = *(const short8*)(arow + 512 + (size_t)kt * 32);
#pragma unroll
        for (int kt = 0; kt < 16; ++kt) {
            v4f* a = (kt & 3) == 0 ? &ac0 : (kt & 3) == 1 ? &ac1 : (kt & 3) == 2 ? &ac2 : &ac3;
            *a = __builtin_amdgcn_mfma_f32_16x16x32_bf16(af[kt], wf[16 + kt], *a, 0, 0, 0);
        }
        v4f acc = (ac0 + ac1) + (ac2 + ac3);

        // h values for this lane: (batch eb+q, col en)
        float hv[4];
#pragma unroll
        for (int q = 0; q < 4; ++q)
            hv[q] = tanhf(acc[q] + xv[q]);

        // publish write-through: pair lanes -> 4B words, 2 stores/lane
#pragma unroll
        for (int q = 0; q < 4; ++q) {
            float pv = __shfl_xor(hv[q], 1);
            bool mine = ((lane & 1) == 0) ? (q < 2) : (q >= 2);
            if (mine) {
                uint32_t word = (lane & 1) ? pack2(pv, hv[q]) : pack2(hv[q], pv);
                size_t i32 = (((size_t)(eb + q) * T_SEQ + t) * H_DIM + (size_t)(en & ~1)) >> 1;
                __hip_atomic_store(&Hb32[i32], word, __ATOMIC_RELAXED,
                                   __HIP_MEMORY_SCOPE_AGENT);
            }
        }

        if (t < T_SEQ - 1) {
            __syncthreads();   // drains each wave's stores (vmcnt 0 before s_barrier)
            if (tid == 0)
                __hip_atomic_store(myflag, (uint32_t)(t + 1), __ATOMIC_RELEASE,
                                   __HIP_MEMORY_SCOPE_AGENT);
            if (tid < 16) {
                const uint32_t* f = grpflags + (size_t)tid * 32;
                while (__hip_atomic_load(f, __ATOMIC_RELAXED,
                                         __HIP_MEMORY_SCOPE_AGENT) <= (uint32_t)t)
                    __builtin_amdgcn_s_sleep(2);
            }
            if (tid == 0)
                (void)__hip_atomic_load(myflag, __ATOMIC_ACQUIRE,
                                        __HIP_MEMORY_SCOPE_AGENT);  // L1+L2 inv
            __syncthreads();
        }
    }
}

// ---------------------------------------------------------------------------
// kgemm: out[m][gc0+n] = sum_k Hb[m][k] * WbChunk[n][k] + b_out[gc0+n]
// bf16 MFMA 16x16x32, 128x128 tile, BK=32, 4 waves, global_load_lds staging.
// Per chunk: 50 nt x 32 mt, bid = nt*32 + mt (A panel L3-reused).
// ---------------------------------------------------------------------------
__global__ __launch_bounds__(256) void kgemm(const uint16_t* __restrict__ Ab,
                                             const uint16_t* __restrict__ Bb,
                                             const float* __restrict__ bout,
                                             float* __restrict__ out,
                                             int gc0) {
    __shared__ __align__(16) uint16_t As[128 * 32];
    __shared__ __align__(16) uint16_t Bs[128 * 32];

    int bid = blockIdx.x;
    int nt = bid >> 5, mt = bid & 31;
    int m0 = mt * 128, n0 = nt * 128;
    int tid = threadIdx.x;
    int lane = tid & 63;

    v4f acc[4][4] = {};
    int wv = tid >> 6, wm = wv >> 1, wn = wv & 1;
    int ar = lane & 15, ko = (lane >> 4) * 8;

    for (int k0 = 0; k0 < H_DIM; k0 += 32) {
        int wb = tid & ~63;   // wave-uniform base (16B units)
#pragma unroll
        for (int l = 0; l < 2; ++l) {
            int c = tid + l * 256;
            int r = c >> 2, ko8 = (c & 3) * 8;
            gload16(&Ab[(size_t)(m0 + r) * H_DIM + k0 + ko8],
                    (char*)As + (size_t)(wb + l * 256) * 16);
            gload16(&Bb[(size_t)(n0 + r) * H_DIM + k0 + ko8],
                    (char*)Bs + (size_t)(wb + l * 256) * 16);
        }
        __syncthreads();

        short8 a[4], bfr[4];
#pragma unroll
        for (int i = 0; i < 4; ++i)
            a[i] = *(const short8*)&As[(wm * 64 + i * 16 + ar) * 32 + ko];
#pragma unroll
        for (int jj = 0; jj < 4; ++jj)
            bfr[jj] = *(const short8*)&Bs[(wn * 64 + jj * 16 + ar) * 32 + ko];
#pragma unroll
        for (int i = 0; i < 4; ++i)
#pragma unroll
            for (int jj = 0; jj < 4; ++jj)
                acc[i][jj] = __builtin_amdgcn_mfma_f32_16x16x32_bf16(
                    a[i], bfr[jj], acc[i][jj], 0, 0, 0);
        __syncthreads();
    }

    int fr = lane & 15, fq = lane >> 4;
#pragma unroll
    for (int jj = 0; jj < 4; ++jj) {
        int col = gc0 + n0 + wn * 64 + jj * 16 + fr;
        float bo = bout[col];
#pragma unroll
        for (int i = 0; i < 4; ++i) {
            int row = m0 + wm * 64 + i * 16 + fq * 4;
#pragma unroll
            for (int q = 0; q < 4; ++q)
                out[(size_t)(row + q) * V_DIM + col] = acc[i][jj][q] + bo;
        }
    }
}

// ---------------------------------------------------------------------------
extern "C" void kernel_launch(void* const* d_in, const int* in_sizes, int n_in,
                              void* d_out, int out_size, void* d_ws, size_t ws_size,
                              hipStream_t stream) {
    const int*   target = (const int*)d_in[0];
    const float* h0     = (const float*)d_in[1];
    const float* emb    = (const float*)d_in[2];
    const float* Wih    = (const float*)d_in[3];
    const float* bih    = (const float*)d_in[4];
    const float* Whh    = (const float*)d_in[5];
    const float* bhh    = (const float*)d_in[6];
    const float* Wout   = (const float*)d_in[7];
    const float* bout   = (const float*)d_in[8];
    float* out = (float*)d_out;

    char* ws = (char*)d_ws;
    // ws layout (bytes) — total 27,332,608:
    float*    xW     = (float*)(ws);                    // 16,777,216
    uint16_t* WbHH   = (uint16_t*)(ws + 16777216);      //  2,097,152
    uint16_t* hbInit = (uint16_t*)(ws + 18874368);      //     65,536
    uint32_t* flags  = (uint32_t*)(ws + 18939904);      //      4,096
    uint16_t* Hb     = (uint16_t*)(ws + 18944000);      //  8,388,608
    uint16_t* WbOut  = (uint16_t*)(ws);                 // 13,107,200 (reuses dead xW)

    kconv<<<512, 256, 0, stream>>>(Whh, WbHH);       // 1,048,576 elts
    kconv<<<16, 256, 0, stream>>>(h0, hbInit);       //    32,768 elts
    kxw<<<dim3(32, 8), 256, 0, stream>>>(target, emb, Wih, bih, bhh, xW);
    hipMemsetAsync(flags, 0, 4096, stream);
    krnn<<<32, 256, 0, stream>>>(hbInit, WbHH, xW, Hb, flags);

    // decode GEMM in 5 column chunks of 6400 (WbOut lives in dead xW region)
    for (int c = 0; c < 5; ++c) {
        kconv<<<3200, 256, 0, stream>>>(Wout + (size_t)c * 6553600, WbOut);
        kgemm<<<1600, 256, 0, stream>>>(Hb, WbOut, bout, out, c * 6400);
    }
}